// Round 1
// baseline (122.564 us; speedup 1.0000x reference)
//
#include <hip/hip_runtime.h>

#define NEURONS 8192
#define INSIZE  8192
#define BATCH   2048
#define ROWS    2          // batch rows staged in LDS per block
#define TPB     512        // threads per block (8 waves)

// ---------------------------------------------------------------------------
// Kernel 1: per-neuron softmax over 16 gate logits -> 4 affine coefficients.
// out[b,n] = C0 + C1*a1 + C2*a2 + C3*a1*a2
// ---------------------------------------------------------------------------
__global__ __launch_bounds__(256) void coef_kernel(const float* __restrict__ w,
                                                   float4* __restrict__ coef) {
    int n = blockIdx.x * blockDim.x + threadIdx.x;
    if (n >= NEURONS) return;

    const float4* w4 = reinterpret_cast<const float4*>(w + (size_t)n * 16);
    float4 v0 = w4[0], v1 = w4[1], v2 = w4[2], v3 = w4[3];
    float p[16] = {v0.x, v0.y, v0.z, v0.w,
                   v1.x, v1.y, v1.z, v1.w,
                   v2.x, v2.y, v2.z, v2.w,
                   v3.x, v3.y, v3.z, v3.w};

    float m = p[0];
    #pragma unroll
    for (int i = 1; i < 16; ++i) m = fmaxf(m, p[i]);
    float s = 0.f;
    #pragma unroll
    for (int i = 0; i < 16; ++i) { p[i] = expf(p[i] - m); s += p[i]; }
    float inv = 1.f / s;
    #pragma unroll
    for (int i = 0; i < 16; ++i) p[i] *= inv;

    float c0 = p[8] + p[9] + p[10] + p[11] + p[12] + p[13] + p[14] + p[15];
    float c1 = p[2] + p[3] + p[6] + p[7] - p[8] - p[9] - p[12] - p[13];
    float c2 = p[4] + p[5] + p[6] + p[7] - p[8] - p[9] - p[10] - p[11];
    float c3 = p[1] - p[2] - p[4] - 2.f * p[6] - p[7]
             + p[8] + 2.f * p[9] + p[11] + p[13] - p[14];

    coef[n] = make_float4(c0, c1, c2, c3);
}

// ---------------------------------------------------------------------------
// Kernel 2: stage ROWS x-rows in LDS, sweep neurons.
// Coalesced: x staging (float4), idx (int2), coef (float4), out stores (4B).
// Random gathers hit LDS only.
// ---------------------------------------------------------------------------
__global__ __launch_bounds__(TPB) void logic_kernel(const float* __restrict__ x,
                                                    const int2* __restrict__ idx,
                                                    const float4* __restrict__ coef,
                                                    float* __restrict__ out) {
    __shared__ float xs[ROWS * INSIZE];   // 64 KiB

    const int b0 = blockIdx.x * ROWS;

    // Stage ROWS full rows of x, vectorized.
    const float4* xrow = reinterpret_cast<const float4*>(x + (size_t)b0 * INSIZE);
    float4* xs4 = reinterpret_cast<float4*>(xs);
    const int nvec = ROWS * INSIZE / 4;   // 4096
    #pragma unroll 4
    for (int i = threadIdx.x; i < nvec; i += TPB) xs4[i] = xrow[i];
    __syncthreads();

    float* out0 = out + (size_t)b0 * NEURONS;

    #pragma unroll 2
    for (int k = 0; k < NEURONS / TPB; ++k) {
        const int n = threadIdx.x + k * TPB;
        const int2  ii = idx[n];
        const float4 c = coef[n];
        #pragma unroll
        for (int r = 0; r < ROWS; ++r) {
            const float a1 = xs[r * INSIZE + ii.x];
            const float a2 = xs[r * INSIZE + ii.y];
            out0[(size_t)r * NEURONS + n] = c.x + c.y * a1 + c.z * a2 + c.w * a1 * a2;
        }
    }
}

extern "C" void kernel_launch(void* const* d_in, const int* in_sizes, int n_in,
                              void* d_out, int out_size, void* d_ws, size_t ws_size,
                              hipStream_t stream) {
    const float* x   = (const float*)d_in[0];
    const float* w   = (const float*)d_in[1];
    const int2*  idx = (const int2*)d_in[2];
    float* out = (float*)d_out;
    float4* coef = (float4*)d_ws;   // 8192 * 16 B = 128 KiB scratch

    coef_kernel<<<NEURONS / 256, 256, 0, stream>>>(w, coef);
    logic_kernel<<<BATCH / ROWS, TPB, 0, stream>>>(x, idx, coef, out);
}